// Round 5
// baseline (370.658 us; speedup 1.0000x reference)
//
#include <hip/hip_runtime.h>

// ---------------------------------------------------------------------------
// TiedRowAxialAttention on MI355X (gfx950), bf16 MFMA pipeline.
// dims: b=4 rows=64 t=256 dim=512 heads=8 dim_head=64 ; scale = 1/64
// stages:
//   prep:   x->bf16 ; W_qkv permuted (d,k,h)->(k,h,d) + bf16 ; W0->bf16
//   gemm1:  qkv = x @ Wp^T (M=65536,N=1536,K=512) -> Q[bh][i][rd], K[bh][j][rd],
//           Vt[bh][rd][j]  -- 512x128 3-buf pipelined mainloop, XCD swizzle,
//           operand-swapped MFMA for Q/K so epilogue stores are ushort4
//   gemm_s: S[bh][i][j] = sum_rd Q K (batched NT, split-K=4, fp32, swap->float4)
//   softmax: wave-per-row, P = softmax(S/64) bf16 (rinv folded in)
//   gemm_pv: O = P V via A=Vt,B=P (M=4096 rd, N=256 i, K=256), pipelined loop
//   gemm2:  out = O2 @ W0^T -> fp32 (swap -> float4 stores)
// ---------------------------------------------------------------------------

typedef short  bf16x8 __attribute__((ext_vector_type(8)));
typedef float  f32x4  __attribute__((ext_vector_type(4)));

#define MFMA16(a,b,c) __builtin_amdgcn_mfma_f32_16x16x32_bf16((a),(b),(c),0,0,0)

__device__ __forceinline__ ushort f2bf(float f) {
  union { float f; unsigned u; } v; v.f = f;
  unsigned r = v.u + 0x7fffu + ((v.u >> 16) & 1u);   // RNE
  return (ushort)(r >> 16);
}

__device__ __forceinline__ void gload_lds16(const void* g, void* lds) {
  __builtin_amdgcn_global_load_lds(
      (const __attribute__((address_space(1))) void*)g,
      (__attribute__((address_space(3))) void*)lds, 16, 0, 0);
}

// -------------------------------- prep -------------------------------------

__global__ void cast_f32_to_bf16(const float* __restrict__ in,
                                 ushort* __restrict__ out, int n4) {
  int idx = blockIdx.x * blockDim.x + threadIdx.x;
  int stride = gridDim.x * blockDim.x;
  for (int v = idx; v < n4; v += stride) {
    float4 f = reinterpret_cast<const float4*>(in)[v];
    ushort4 o; o.x = f2bf(f.x); o.y = f2bf(f.y); o.z = f2bf(f.z); o.w = f2bf(f.w);
    reinterpret_cast<ushort4*>(out)[v] = o;
  }
}

// Wp[n'][c], n' = (k*8+h)*64+d  <-  W_qkv[d*24+k*8+h][c]
__global__ void permute_wqkv_k(const float* __restrict__ W, ushort* __restrict__ Wp) {
  int np = blockIdx.x;                    // 0..1535
  int k = np >> 9, h = (np >> 6) & 7, d = np & 63;
  const float4* s = reinterpret_cast<const float4*>(W + (size_t)(d * 24 + k * 8 + h) * 512);
  ushort4* o = reinterpret_cast<ushort4*>(Wp + (size_t)np * 512);
  for (int c = threadIdx.x; c < 128; c += blockDim.x) {
    float4 f = s[c];
    ushort4 u; u.x = f2bf(f.x); u.y = f2bf(f.y); u.z = f2bf(f.z); u.w = f2bf(f.w);
    o[c] = u;
  }
}

// ================= 512x128 pipelined NT mainloop (8 waves) ==================
// C = A @ B^T ; A [M][lda], B [N][ldb] bf16 row-major, K = 32*P.
// 512 threads = 8 waves (4M x 2N), per-wave 128x64 out = acc[8][4] 16x16 frags.
// BK=32, 3 LDS K-tile buffers (A 32KB + B 8KB each), 2-tile prefetch lead,
// counted vmcnt(5) once per K-tile (never 0 in steady state).
// swap=false: frag rows(kl,j)=m-side, cols(il)=n-side.
// swap=true : operands exchanged -> rows(kl,j)=n-side, cols(il)=m-side.

__device__ __forceinline__ void gemm_nt_512x128(
    const ushort* __restrict__ A, const ushort* __restrict__ B,
    int lda, int ldb, int P, int m0, int n0, char* lds, bool swap,
    f32x4 (&acc)[8][4]) {
  const int tid = threadIdx.x;
  const int w = tid >> 6, l = tid & 63;
  const int il = l & 15, kl = l >> 4;
  const int wm = w >> 1, wn = w & 1;

  auto stageA_half = [&](char* buf, int kt, int half) {
#pragma unroll
    for (int c = 0; c < 2; ++c) {
      int rbase = (half << 8) + (w << 5) + (c << 4);        // wave-uniform
      int row = rbase + (l >> 2);
      int s = ((l & 3) - ((row >> 1) & 3)) & 3;
      const ushort* g = A + (size_t)(m0 + row) * lda + (kt << 5) + (s << 3);
      gload_lds16(g, buf + rbase * 64);
    }
  };
  auto stageB = [&](char* buf, int kt) {
    int rbase = (w << 4);                                   // wave-uniform
    int row = rbase + (l >> 2);
    int s = ((l & 3) - ((row >> 1) & 3)) & 3;
    const ushort* g = B + (size_t)(n0 + row) * ldb + (kt << 5) + (s << 3);
    gload_lds16(g, buf + 32768 + rbase * 64);
  };
  auto loadA4 = [&](const char* abuf, int fmbase, bf16x8 (&af)[4]) {
#pragma unroll
    for (int q = 0; q < 4; ++q) {
      int row = (wm << 7) + ((fmbase + q) << 4) + il;
      af[q] = *(const bf16x8*)(abuf + row * 64 + (((kl + (row >> 1)) & 3) << 4));
    }
  };
  auto loadB4 = [&](const char* bbuf, bf16x8 (&bfr)[4]) {
#pragma unroll
    for (int q = 0; q < 4; ++q) {
      int row = (wn << 6) + (q << 4) + il;
      bfr[q] = *(const bf16x8*)(bbuf + 32768 + row * 64 + (((kl + (row >> 1)) & 3) << 4));
    }
  };

#pragma unroll
  for (int i = 0; i < 8; ++i)
#pragma unroll
    for (int j = 0; j < 4; ++j) acc[i][j] = f32x4{0.f, 0.f, 0.f, 0.f};

  // prologue: stage tiles 0,1 (5 vmem ops each); t0 must be resident.
  {
    char* b0 = lds;
    char* b1 = lds + 40960;
    stageA_half(b0, 0, 0); stageB(b0, 0); stageA_half(b0, 0, 1);
    stageA_half(b1, 1, 0); stageB(b1, 1); stageA_half(b1, 1, 1);
    asm volatile("s_waitcnt vmcnt(5)" ::: "memory");
    __builtin_amdgcn_s_barrier();
  }

  int cur = 0, n2 = 2;
  for (int g = 0; g < P; ++g) {
    char* cbuf = lds + cur * 40960;
    char* sbuf = lds + n2 * 40960;
    const bool pf = (g + 2 < P);
    bf16x8 bfr[4];
    // ---- phase 0: fm 0..3 (8 ds_reads; stage A-half0 + B of tile g+2) ----
    {
      bf16x8 af[4];
      loadA4(cbuf, 0, af);
      loadB4(cbuf, bfr);
      if (pf) { stageA_half(sbuf, g + 2, 0); stageB(sbuf, g + 2); }
      __builtin_amdgcn_s_barrier();
      asm volatile("s_waitcnt lgkmcnt(0)" ::: "memory");
      __builtin_amdgcn_sched_barrier(0);
      __builtin_amdgcn_s_setprio(1);
      if (swap) {
#pragma unroll
        for (int fm = 0; fm < 4; ++fm)
#pragma unroll
          for (int fn = 0; fn < 4; ++fn)
            acc[fm][fn] = MFMA16(bfr[fn], af[fm], acc[fm][fn]);
      } else {
#pragma unroll
        for (int fm = 0; fm < 4; ++fm)
#pragma unroll
          for (int fn = 0; fn < 4; ++fn)
            acc[fm][fn] = MFMA16(af[fm], bfr[fn], acc[fm][fn]);
      }
      __builtin_amdgcn_s_setprio(0);
      __builtin_amdgcn_s_barrier();
    }
    // ---- phase 1: fm 4..7 (4 ds_reads; stage A-half1; counted vmcnt) ----
    {
      bf16x8 af[4];
      loadA4(cbuf, 4, af);
      if (pf) stageA_half(sbuf, g + 2, 1);
      if (pf)                asm volatile("s_waitcnt vmcnt(5)" ::: "memory");
      else if (g + 1 < P)    asm volatile("s_waitcnt vmcnt(0)" ::: "memory");
      __builtin_amdgcn_s_barrier();
      asm volatile("s_waitcnt lgkmcnt(0)" ::: "memory");
      __builtin_amdgcn_sched_barrier(0);
      __builtin_amdgcn_s_setprio(1);
      if (swap) {
#pragma unroll
        for (int fm = 0; fm < 4; ++fm)
#pragma unroll
          for (int fn = 0; fn < 4; ++fn)
            acc[4 + fm][fn] = MFMA16(bfr[fn], af[fm], acc[4 + fm][fn]);
      } else {
#pragma unroll
        for (int fm = 0; fm < 4; ++fm)
#pragma unroll
          for (int fn = 0; fn < 4; ++fn)
            acc[4 + fm][fn] = MFMA16(af[fm], bfr[fn], acc[4 + fm][fn]);
      }
      __builtin_amdgcn_s_setprio(0);
      __builtin_amdgcn_s_barrier();
    }
    cur = (cur == 2) ? 0 : cur + 1;
    n2  = (n2  == 2) ? 0 : n2  + 1;
  }
}

// ------------------------------- gemm1 (qkv) --------------------------------
// 1536 blocks linear; XCD swizzle keeps the 12 n-tiles of one 512-row A panel
// on one XCD's L2. Q/K: swapped MFMA -> per-thread n-contiguous -> ushort4.

__global__ __launch_bounds__(512, 2) void gemm_qkv_k(
    const ushort* __restrict__ xb, const ushort* __restrict__ Wp,
    ushort* __restrict__ Qb, ushort* __restrict__ Kb, ushort* __restrict__ Vt) {
  __shared__ __align__(16) char lds[122880];
  f32x4 acc[8][4];
  const int Bid = blockIdx.x;
  const int xcd = Bid & 7, idx = Bid >> 3;
  const int nt = idx % 12, pl = idx / 12;       // pl 0..15
  const int m0 = ((pl << 3) + xcd) << 9;        // 128 m-tiles * 512
  const int n0 = nt << 7;
  const int kq = n0 >> 9;                       // block-uniform: 0=Q 1=K 2=V
  gemm_nt_512x128(xb, Wp, 512, 512, 16, m0, n0, lds, kq < 2, acc);

  const int tid = threadIdx.x, w = tid >> 6, l = tid & 63;
  const int il = l & 15, kl = l >> 4;
  const int wm = w >> 1, wn = w & 1;

  if (kq < 2) {
    // swapped frags: m-side <- il ; n-side <- kl*4 + j (contiguous d)
    ushort* dstb = kq ? Kb : Qb;
#pragma unroll
    for (int fm = 0; fm < 8; ++fm) {
      int m = m0 + (wm << 7) + (fm << 4) + il;
      int i = m & 255, br = m >> 8, b = br >> 6, r = br & 63;
      int h_i_base = (((b << 3)) << 8) + i;     // h added below
#pragma unroll
      for (int fn = 0; fn < 4; ++fn) {
        int n = n0 + (wn << 6) + (fn << 4) + (kl << 2);
        int h = (n >> 6) & 7, d0 = n & 63;
        size_t dst = ((size_t)(h_i_base + (h << 8)) << 12) + (r << 6) + d0;
        ushort4 pk; pk.x = f2bf(acc[fm][fn][0]); pk.y = f2bf(acc[fm][fn][1]);
        pk.z = f2bf(acc[fm][fn][2]); pk.w = f2bf(acc[fm][fn][3]);
        *reinterpret_cast<ushort4*>(&dstb[dst]) = pk;
      }
    }
  } else {
    // unswapped: m-side (i) <- kl*4 + j contiguous -> ushort4 along Vt inner dim
#pragma unroll
    for (int fm = 0; fm < 8; ++fm)
#pragma unroll
      for (int fn = 0; fn < 4; ++fn) {
        int n = n0 - 1024 + (wn << 6) + (fn << 4) + il;     // h*64+d
        int h = n >> 6, d = n & 63;
        int m = m0 + (wm << 7) + (fm << 4) + (kl << 2);
        int i0 = m & 255, br = m >> 8, b = br >> 6, r = br & 63;
        size_t dst = (((size_t)((((b << 3) + h) << 12)) + (r << 6) + d) << 8) + i0;
        ushort4 pk; pk.x = f2bf(acc[fm][fn][0]); pk.y = f2bf(acc[fm][fn][1]);
        pk.z = f2bf(acc[fm][fn][2]); pk.w = f2bf(acc[fm][fn][3]);
        *reinterpret_cast<ushort4*>(&Vt[dst]) = pk;   // 4 consecutive i
      }
  }
}

// ------------------------------- gemm2 (out) --------------------------------
// 512 blocks linear; XCD swizzle; swapped MFMA -> float4 stores.

__global__ __launch_bounds__(512, 2) void gemm_out_k(
    const ushort* __restrict__ O2, const ushort* __restrict__ W0b,
    float* __restrict__ out) {
  __shared__ __align__(16) char lds[122880];
  f32x4 acc[8][4];
  const int Bid = blockIdx.x;
  const int xcd = Bid & 7, idx = Bid >> 3;
  const int nt = idx & 3, pl = idx >> 2;        // pl 0..15
  const int m0 = ((pl << 3) + xcd) << 9;
  const int n0 = nt << 7;
  gemm_nt_512x128(O2, W0b, 512, 512, 16, m0, n0, lds, true, acc);

  const int tid = threadIdx.x, w = tid >> 6, l = tid & 63;
  const int il = l & 15, kl = l >> 4;
  const int wm = w >> 1, wn = w & 1;
#pragma unroll
  for (int fm = 0; fm < 8; ++fm) {
    int m = m0 + (wm << 7) + (fm << 4) + il;
#pragma unroll
    for (int fn = 0; fn < 4; ++fn) {
      int n = n0 + (wn << 6) + (fn << 4) + (kl << 2);
      *reinterpret_cast<f32x4*>(&out[(size_t)m * 512 + n]) = acc[fm][fn];
    }
  }
}

// ---------------------- gemm_pv: O = P V  (A=Vt, B=P) -----------------------
// Pipelined 512x128 loop. 512 blocks; XCD swizzle groups one bh's 16 blocks.
// Unswapped: m-side (rd) j-contiguous -> ushort4 along d.

__global__ __launch_bounds__(512, 2) void gemm_pv_k(
    const ushort* __restrict__ Vt, const ushort* __restrict__ Pb,
    ushort* __restrict__ O2) {
  __shared__ __align__(16) char lds[122880];
  f32x4 acc[8][4];
  const int Bid = blockIdx.x;
  const int xcd = Bid & 7, idx = Bid >> 3;      // idx 0..63
  const int sub = idx & 15, grp = idx >> 4;     // sub: mt*2+nt, grp 0..3
  const int bh = (grp << 3) + xcd, b = bh >> 3, h = bh & 7;
  const int m0 = (sub >> 1) << 9;               // rd tile (8 x 512)
  const int n0 = (sub & 1) << 7;                // i tile (2 x 128)
  gemm_nt_512x128(Vt + ((size_t)bh << 20), Pb + ((size_t)bh << 16),
                  256, 256, 8, m0, n0, lds, false, acc);

  const int tid = threadIdx.x, w = tid >> 6, l = tid & 63;
  const int il = l & 15, kl = l >> 4;
  const int wm = w >> 1, wn = w & 1;
#pragma unroll
  for (int fm = 0; fm < 8; ++fm) {
    int rd0 = m0 + (wm << 7) + (fm << 4) + (kl << 2);
    int r = rd0 >> 6, d0 = rd0 & 63;
#pragma unroll
    for (int fn = 0; fn < 4; ++fn) {
      int i = n0 + (wn << 6) + (fn << 4) + il;
      ushort4 pk; pk.x = f2bf(acc[fm][fn][0]); pk.y = f2bf(acc[fm][fn][1]);
      pk.z = f2bf(acc[fm][fn][2]); pk.w = f2bf(acc[fm][fn][3]);
      *reinterpret_cast<ushort4*>(
          O2 + ((size_t)((((b << 6) + r) << 8) + i) << 9) + (h << 6) + d0) = pk;
    }
  }
}

// ------------------------- shared 128x128 NT mainloop -----------------------
// (kept for gemm_s) C = A @ B^T ; 256 thr (4 waves 2x2).

__device__ __forceinline__ void gemm_nt_mainloop_128(
    const ushort* __restrict__ A, const ushort* __restrict__ B,
    int lda, int ldb, int klen, int m0, int n0, ushort* lds, bool swap,
    f32x4 (&acc)[4][4]) {
  const int tid = threadIdx.x;
  const int w = tid >> 6, l = tid & 63;
  const int il = l & 15, kl = l >> 4;

  ushort* ldsA[2] = { lds,         lds + 8192  };
  ushort* ldsB[2] = { lds + 16384, lds + 24576 };

  int srow[4], scs[4], sbase[4];
#pragma unroll
  for (int q = 0; q < 4; ++q) {
    int wb = ((q * 4 + w) << 10);
    int o  = wb + (l << 4);
    int row = o >> 7, c = o & 127;
    srow[q] = row; scs[q] = c ^ ((row & 7) << 4); sbase[q] = wb;
  }

#pragma unroll
  for (int i = 0; i < 4; ++i)
#pragma unroll
    for (int j = 0; j < 4; ++j) acc[i][j] = f32x4{0.f, 0.f, 0.f, 0.f};

  const int NT = klen >> 6;
  const int wr = (w >> 1) << 6, wc = (w & 1) << 6;

  auto stage = [&](int buf, int kt) {
    int kb = kt << 6;
#pragma unroll
    for (int q = 0; q < 4; ++q) {
      gload_lds16(A + (size_t)(m0 + srow[q]) * lda + kb + (scs[q] >> 1),
                  (char*)ldsA[buf] + sbase[q]);
      gload_lds16(B + (size_t)(n0 + srow[q]) * ldb + kb + (scs[q] >> 1),
                  (char*)ldsB[buf] + sbase[q]);
    }
  };

  stage(0, 0);
  __syncthreads();
  for (int kt = 0; kt < NT; ++kt) {
    if (kt + 1 < NT) stage((kt + 1) & 1, kt + 1);
    const ushort* la = ldsA[kt & 1];
    const ushort* lb = ldsB[kt & 1];
    bf16x8 af[2][4], bfr[2][4];
#pragma unroll
    for (int fm = 0; fm < 4; ++fm) {
      int row = wr + (fm << 4) + il, sw = (row & 7) << 4;
#pragma unroll
      for (int kk = 0; kk < 2; ++kk)
        af[kk][fm] = *(const bf16x8*)((const char*)la + row * 128 + ((((kk << 6) + (kl << 4))) ^ sw));
    }
#pragma unroll
    for (int fn = 0; fn < 4; ++fn) {
      int row = wc + (fn << 4) + il, sw = (row & 7) << 4;
#pragma unroll
      for (int kk = 0; kk < 2; ++kk)
        bfr[kk][fn] = *(const bf16x8*)((const char*)lb + row * 128 + ((((kk << 6) + (kl << 4))) ^ sw));
    }
    if (swap) {
#pragma unroll
      for (int kk = 0; kk < 2; ++kk)
#pragma unroll
        for (int fm = 0; fm < 4; ++fm)
#pragma unroll
          for (int fn = 0; fn < 4; ++fn)
            acc[fm][fn] = MFMA16(bfr[kk][fn], af[kk][fm], acc[fm][fn]);
    } else {
#pragma unroll
      for (int kk = 0; kk < 2; ++kk)
#pragma unroll
        for (int fm = 0; fm < 4; ++fm)
#pragma unroll
          for (int fn = 0; fn < 4; ++fn)
            acc[fm][fn] = MFMA16(af[kk][fm], bfr[kk][fn], acc[fm][fn]);
    }
    __syncthreads();
  }
}

// ---------------------- gemm_s: S partials (split-K=4) ----------------------
// 512 blocks linear; XCD swizzle; swapped MFMA -> float4 stores.

__global__ __launch_bounds__(256, 2) void gemm_s_k(
    const ushort* __restrict__ Qb, const ushort* __restrict__ Kb,
    float* __restrict__ Sp) {
  __shared__ __align__(16) ushort lds[32768];
  f32x4 acc[4][4];
  const int Bid = blockIdx.x;
  const int xcd = Bid & 7, idx = Bid >> 3;
  const int sub = idx & 3, zl = idx >> 2;       // zl 0..15
  const int z = (zl << 3) + xcd;                // 0..127
  const int bh = z >> 2, ks = z & 3;
  const int m0 = (sub & 1) << 7, n0 = (sub >> 1) << 7;
  const size_t base = ((size_t)bh << 20) + ((size_t)ks << 10);
  gemm_nt_mainloop_128(Qb + base, Kb + base, 4096, 4096, 1024, m0, n0, lds,
                       true, acc);

  const int tid = threadIdx.x, w = tid >> 6, l = tid & 63;
  const int il = l & 15, kl = l >> 4;
  const int wr = (w >> 1) << 6, wc = (w & 1) << 6;
  float* out = Sp + ((size_t)z << 16);
#pragma unroll
  for (int fm = 0; fm < 4; ++fm) {
    int m = m0 + wr + (fm << 4) + il;
#pragma unroll
    for (int fn = 0; fn < 4; ++fn) {
      int n = n0 + wc + (fn << 4) + (kl << 2);
      *reinterpret_cast<f32x4*>(&out[(size_t)m * 256 + n]) = acc[fm][fn];
    }
  }
}

// ------------------------- softmax (wave per row) ---------------------------

__global__ void softmax_k(const float* __restrict__ Sp, ushort* __restrict__ Pb) {
  const int w = threadIdx.x >> 6, l = threadIdx.x & 63;
  const int row = (blockIdx.x << 2) + w;        // 0..8191
  const int bh = row >> 8, i = row & 255;
  const float4* p0 = reinterpret_cast<const float4*>(
      Sp + (((size_t)bh << 2) << 16) + ((size_t)i << 8)) + l;
  float4 a = p0[0], b2 = p0[16384], c = p0[32768], d = p0[49152];
  const float scale = 0.015625f;
  float s0 = (a.x + b2.x + c.x + d.x) * scale;
  float s1 = (a.y + b2.y + c.y + d.y) * scale;
  float s2 = (a.z + b2.z + c.z + d.z) * scale;
  float s3 = (a.w + b2.w + c.w + d.w) * scale;
  float m = fmaxf(fmaxf(s0, s1), fmaxf(s2, s3));
#pragma unroll
  for (int d2 = 1; d2 < 64; d2 <<= 1) m = fmaxf(m, __shfl_xor(m, d2));
  float e0 = __expf(s0 - m), e1 = __expf(s1 - m);
  float e2 = __expf(s2 - m), e3 = __expf(s3 - m);
  float sum = e0 + e1 + e2 + e3;
#pragma unroll
  for (int d2 = 1; d2 < 64; d2 <<= 1) sum += __shfl_xor(sum, d2);
  float r = 1.0f / sum;
  ushort4 p; p.x = f2bf(e0 * r); p.y = f2bf(e1 * r);
  p.z = f2bf(e2 * r); p.w = f2bf(e3 * r);
  reinterpret_cast<ushort4*>(Pb + ((size_t)bh << 16) + ((size_t)i << 8))[l] = p;
}

// ------------------------------- launcher -----------------------------------

extern "C" void kernel_launch(void* const* d_in, const int* in_sizes, int n_in,
                              void* d_out, int out_size, void* d_ws, size_t ws_size,
                              hipStream_t stream) {
  const float* x    = (const float*)d_in[0];
  const float* Wqkv = (const float*)d_in[1];
  const float* W0   = (const float*)d_in[2];
  float* out = (float*)d_out;

  char* ws = (char*)d_ws;
  ushort* xb  = (ushort*)(ws);                    // 67,108,864 B (-> Sp -> O2)
  ushort* Wp  = (ushort*)(ws + 67108864);         //  1,572,864
  ushort* W0b = (ushort*)(ws + 68681728);         //    524,288
  ushort* Qb  = (ushort*)(ws + 69206016);         // 67,108,864 (-> Pb)
  ushort* Kb  = (ushort*)(ws + 136314880);        // 67,108,864
  ushort* Vt  = (ushort*)(ws + 203423744);        // 67,108,864  -> total 270,532,608
  if (ws_size < 270532608ull) return;             // workspace too small: fail visibly

  cast_f32_to_bf16<<<2048, 256, 0, stream>>>(x, xb, 8388608);
  cast_f32_to_bf16<<<256, 256, 0, stream>>>(W0, W0b, 65536);
  permute_wqkv_k<<<1536, 128, 0, stream>>>(Wqkv, Wp);

  gemm_qkv_k<<<1536, 512, 0, stream>>>(xb, Wp, Qb, Kb, Vt);

  float*  Sp = (float*)xb;                        // xb dead after gemm1 (33.6 MB)
  ushort* Pb = Qb;                                // Qb dead after gemm_s (4.2 MB)
  ushort* O2 = xb;                                // Sp dead after softmax (64 MB)

  gemm_s_k<<<512, 256, 0, stream>>>(Qb, Kb, Sp);
  softmax_k<<<2048, 256, 0, stream>>>(Sp, Pb);
  gemm_pv_k<<<512, 512, 0, stream>>>(Vt, Pb, O2);

  gemm_out_k<<<512, 512, 0, stream>>>(O2, W0b, out);
}

// Round 6
// 304.809 us; speedup vs baseline: 1.2160x; 1.2160x over previous
//
#include <hip/hip_runtime.h>

// ---------------------------------------------------------------------------
// TiedRowAxialAttention on MI355X (gfx950), bf16 MFMA pipeline.
// dims: b=4 rows=64 t=256 dim=512 heads=8 dim_head=64 ; scale = 1/64
// stages:
//   prep:   x->bf16 ; W_qkv permuted (d,k,h)->(k,h,d) + bf16 ; W0->bf16
//   gemm1:  qkv = x @ Wp^T (M=65536,N=1536,K=512) -> Q[bh][i][rd], K[bh][j][rd],
//           Vt[bh][rd][j]
//   gemm_s: S[bh][i][j] = sum_rd Q K (batched NT, split-K=8, fp32 partials)
//   softmax: wave-per-row, P = softmax(S/64) bf16 (rinv folded in)
//   gemm_pv: O = P V via A=Vt,B=P (M=4096 rd, N=256 i, K=256) -> O2[(b,r,i)][hd]
//   gemm2:  out = O2 @ W0^T -> fp32
// All GEMMs share one mainloop: 256x128 tile, BK=32, 8 waves (4Mx2N, 64x64
// each), 3 LDS buffers (72 KB) -> 2 blocks/CU, 2-tile prefetch lead, counted
// vmcnt(3), single barrier per K-tile. Coalesced (unswapped) epilogues.
// ---------------------------------------------------------------------------

typedef short  bf16x8 __attribute__((ext_vector_type(8)));
typedef float  f32x4  __attribute__((ext_vector_type(4)));

#define MFMA16(a,b,c) __builtin_amdgcn_mfma_f32_16x16x32_bf16((a),(b),(c),0,0,0)

__device__ __forceinline__ ushort f2bf(float f) {
  union { float f; unsigned u; } v; v.f = f;
  unsigned r = v.u + 0x7fffu + ((v.u >> 16) & 1u);   // RNE
  return (ushort)(r >> 16);
}

__device__ __forceinline__ void gload_lds16(const void* g, void* lds) {
  __builtin_amdgcn_global_load_lds(
      (const __attribute__((address_space(1))) void*)g,
      (__attribute__((address_space(3))) void*)lds, 16, 0, 0);
}

// -------------------------------- prep -------------------------------------

__global__ void cast_f32_to_bf16(const float* __restrict__ in,
                                 ushort* __restrict__ out, int n4) {
  int idx = blockIdx.x * blockDim.x + threadIdx.x;
  int stride = gridDim.x * blockDim.x;
  for (int v = idx; v < n4; v += stride) {
    float4 f = reinterpret_cast<const float4*>(in)[v];
    ushort4 o; o.x = f2bf(f.x); o.y = f2bf(f.y); o.z = f2bf(f.z); o.w = f2bf(f.w);
    reinterpret_cast<ushort4*>(out)[v] = o;
  }
}

// Wp[n'][c], n' = (k*8+h)*64+d  <-  W_qkv[d*24+k*8+h][c]
__global__ void permute_wqkv_k(const float* __restrict__ W, ushort* __restrict__ Wp) {
  int np = blockIdx.x;                    // 0..1535
  int k = np >> 9, h = (np >> 6) & 7, d = np & 63;
  const float4* s = reinterpret_cast<const float4*>(W + (size_t)(d * 24 + k * 8 + h) * 512);
  ushort4* o = reinterpret_cast<ushort4*>(Wp + (size_t)np * 512);
  for (int c = threadIdx.x; c < 128; c += blockDim.x) {
    float4 f = s[c];
    ushort4 u; u.x = f2bf(f.x); u.y = f2bf(f.y); u.z = f2bf(f.z); u.w = f2bf(f.w);
    o[c] = u;
  }
}

// ================== 256x128 pipelined NT mainloop (8 waves) =================
// C = A @ B^T ; A [M][lda], B [N][ldb] bf16 row-major, K = 32*P.
// 512 threads = 8 waves (4M x 2N), per-wave 64x64 out = acc[4][4] 16x16 frags.
// BK=32, 3 LDS buffers (A 16KB + B 8KB each = 24KB), 2-tile prefetch lead,
// counted vmcnt(3) once per K-tile, one barrier per K-tile.
// LDS per-row slot rotation: storage slot t at row r holds k-slot (t - r>>1)&3
// (stage source pre-rotated; reads use slot (kl + r>>1)&3) -> 2-way max (free).

__device__ __forceinline__ void gemm_nt_256x128(
    const ushort* __restrict__ A, const ushort* __restrict__ B,
    int lda, int ldb, int P, int m0, int n0, char* lds, f32x4 (&acc)[4][4]) {
  const int tid = threadIdx.x;
  const int w = tid >> 6, l = tid & 63;
  const int il = l & 15, kl = l >> 4;
  const int wm = w >> 1, wn = w & 1;

  auto stageA = [&](char* buf, int kt) {
#pragma unroll
    for (int c = 0; c < 2; ++c) {
      int rbase = (w << 5) + (c << 4);                     // wave-uniform
      int row = rbase + (l >> 2);
      int s = ((l & 3) - ((row >> 1) & 3)) & 3;
      gload_lds16(A + (size_t)(m0 + row) * lda + (kt << 5) + (s << 3),
                  buf + rbase * 64);
    }
  };
  auto stageB = [&](char* buf, int kt) {
    int rbase = (w << 4);                                  // wave-uniform
    int row = rbase + (l >> 2);
    int s = ((l & 3) - ((row >> 1) & 3)) & 3;
    gload_lds16(B + (size_t)(n0 + row) * ldb + (kt << 5) + (s << 3),
                buf + 16384 + rbase * 64);
  };
  auto loadA4 = [&](const char* buf, bf16x8 (&af)[4]) {
#pragma unroll
    for (int q = 0; q < 4; ++q) {
      int row = (wm << 6) + (q << 4) + il;
      af[q] = *(const bf16x8*)(buf + row * 64 + (((kl + (row >> 1)) & 3) << 4));
    }
  };
  auto loadB4 = [&](const char* buf, bf16x8 (&bfr)[4]) {
#pragma unroll
    for (int q = 0; q < 4; ++q) {
      int row = (wn << 6) + (q << 4) + il;
      bfr[q] = *(const bf16x8*)(buf + 16384 + row * 64 + (((kl + (row >> 1)) & 3) << 4));
    }
  };

#pragma unroll
  for (int i = 0; i < 4; ++i)
#pragma unroll
    for (int j = 0; j < 4; ++j) acc[i][j] = f32x4{0.f, 0.f, 0.f, 0.f};

  // prologue: stage tiles 0,1 (3 vmem ops each); t0 must be resident.
  stageA(lds, 0);         stageB(lds, 0);
  stageA(lds + 24576, 1); stageB(lds + 24576, 1);
  asm volatile("s_waitcnt vmcnt(3)" ::: "memory");
  __builtin_amdgcn_s_barrier();

  int cur = 0, nx = 2;
  for (int g = 0; g < P; ++g) {
    char* cbuf = lds + cur * 24576;
    char* sbuf = lds + nx * 24576;
    bf16x8 af[4], bfr[4];
    loadA4(cbuf, af);
    loadB4(cbuf, bfr);
    if (g + 2 < P) { stageA(sbuf, g + 2); stageB(sbuf, g + 2); }
    asm volatile("s_waitcnt lgkmcnt(0)" ::: "memory");
    __builtin_amdgcn_sched_barrier(0);
    __builtin_amdgcn_s_setprio(1);
#pragma unroll
    for (int fm = 0; fm < 4; ++fm)
#pragma unroll
      for (int fn = 0; fn < 4; ++fn)
        acc[fm][fn] = MFMA16(af[fm], bfr[fn], acc[fm][fn]);
    __builtin_amdgcn_s_setprio(0);
    if (g + 2 < P) asm volatile("s_waitcnt vmcnt(3)" ::: "memory");
    else           asm volatile("s_waitcnt vmcnt(0)" ::: "memory");
    __builtin_amdgcn_s_barrier();
    cur = (cur == 2) ? 0 : cur + 1;
    nx  = (nx  == 2) ? 0 : nx  + 1;
  }
}

// ------------------------------- gemm1 (qkv) --------------------------------
// 3072 blocks; XCD swizzle: the 12 n-tiles of one A-panel group stay together.

__global__ __launch_bounds__(512, 4) void gemm_qkv_k(
    const ushort* __restrict__ xb, const ushort* __restrict__ Wp,
    ushort* __restrict__ Qb, ushort* __restrict__ Kb, ushort* __restrict__ Vt) {
  __shared__ __align__(16) char lds[73728];
  f32x4 acc[4][4];
  const int Bid = blockIdx.x;
  const int xcd = Bid & 7, idx = Bid >> 3;
  const int nt = idx % 12, pl = idx / 12;       // pl 0..31
  const int m0 = ((pl << 3) + xcd) << 8;        // 256 m-tiles * 256
  const int n0 = nt << 7;
  gemm_nt_256x128(xb, Wp, 512, 512, 16, m0, n0, lds, acc);

  const int tid = threadIdx.x, w = tid >> 6, l = tid & 63;
  const int il = l & 15, kl = l >> 4;
  const int wm = w >> 1, wn = w & 1;
  const int kq = n0 >> 9;                       // block-uniform: 0=Q 1=K 2=V
  const int br = m0 >> 8, b = br >> 6, r = br & 63;   // one (b,r) per block

  if (kq < 2) {
    ushort* dstb = kq ? Kb : Qb;
#pragma unroll
    for (int fm = 0; fm < 4; ++fm)
#pragma unroll
      for (int fn = 0; fn < 4; ++fn) {
        int n = n0 + (wn << 6) + (fn << 4) + il;
        int h = (n >> 6) & 7, d = n & 63;
#pragma unroll
        for (int j = 0; j < 4; ++j) {
          int i = (wm << 6) + (fm << 4) + (kl << 2) + j;
          size_t dst = ((size_t)((((b << 3) + h) << 8) + i) << 12) + (r << 6) + d;
          dstb[dst] = f2bf(acc[fm][fn][j]);     // lanes: 2B x16 contiguous in d
        }
      }
  } else {
#pragma unroll
    for (int fm = 0; fm < 4; ++fm)
#pragma unroll
      for (int fn = 0; fn < 4; ++fn) {
        int n = n0 - 1024 + (wn << 6) + (fn << 4) + il;     // h*64+d
        int h = n >> 6, d = n & 63;
        int i0 = (wm << 6) + (fm << 4) + (kl << 2);
        size_t dst = (((size_t)((((b << 3) + h) << 12)) + (r << 6) + d) << 8) + i0;
        ushort4 pk; pk.x = f2bf(acc[fm][fn][0]); pk.y = f2bf(acc[fm][fn][1]);
        pk.z = f2bf(acc[fm][fn][2]); pk.w = f2bf(acc[fm][fn][3]);
        *reinterpret_cast<ushort4*>(&Vt[dst]) = pk;   // 4 consecutive i
      }
  }
}

// ------------------------------- gemm2 (out) --------------------------------
// 1024 blocks; XCD swizzle; scalar f32 stores (lanes 4B x16 contiguous).

__global__ __launch_bounds__(512, 4) void gemm_out_k(
    const ushort* __restrict__ O2, const ushort* __restrict__ W0b,
    float* __restrict__ out) {
  __shared__ __align__(16) char lds[73728];
  f32x4 acc[4][4];
  const int Bid = blockIdx.x;
  const int xcd = Bid & 7, idx = Bid >> 3;
  const int nt = idx & 3, pl = idx >> 2;        // pl 0..31
  const int m0 = ((pl << 3) + xcd) << 8;
  const int n0 = nt << 7;
  gemm_nt_256x128(O2, W0b, 512, 512, 16, m0, n0, lds, acc);

  const int tid = threadIdx.x, w = tid >> 6, l = tid & 63;
  const int il = l & 15, kl = l >> 4;
  const int wm = w >> 1, wn = w & 1;
#pragma unroll
  for (int fm = 0; fm < 4; ++fm)
#pragma unroll
    for (int fn = 0; fn < 4; ++fn) {
      int n = n0 + (wn << 6) + (fn << 4) + il;
#pragma unroll
      for (int j = 0; j < 4; ++j) {
        int m = m0 + (wm << 6) + (fm << 4) + (kl << 2) + j;
        out[(size_t)m * 512 + n] = acc[fm][fn][j];
      }
    }
}

// ---------------------- gemm_s: S partials (split-K=8) ----------------------
// 512 blocks; z = bh*8+ks, each computes a 256x128 slab of S over rd-range
// ks*512..+512. Sp[z][i][j] fp32.

__global__ __launch_bounds__(512, 4) void gemm_s_k(
    const ushort* __restrict__ Qb, const ushort* __restrict__ Kb,
    float* __restrict__ Sp) {
  __shared__ __align__(16) char lds[73728];
  f32x4 acc[4][4];
  const int Bid = blockIdx.x;
  const int xcd = Bid & 7, idx = Bid >> 3;      // idx 0..63
  const int nt = idx & 1, zl = idx >> 1;        // zl 0..31
  const int z = (zl << 3) + xcd;                // 0..255
  const int bh = z >> 3, ks = z & 7;
  const int n0 = nt << 7;
  const size_t base = ((size_t)bh << 20) + ((size_t)ks << 9);
  gemm_nt_256x128(Qb + base, Kb + base, 4096, 4096, 16, 0, n0, lds, acc);

  const int tid = threadIdx.x, w = tid >> 6, l = tid & 63;
  const int il = l & 15, kl = l >> 4;
  const int wm = w >> 1, wn = w & 1;
  float* o = Sp + ((size_t)z << 16);
#pragma unroll
  for (int fm = 0; fm < 4; ++fm)
#pragma unroll
    for (int fn = 0; fn < 4; ++fn) {
      int n = n0 + (wn << 6) + (fn << 4) + il;
#pragma unroll
      for (int j = 0; j < 4; ++j) {
        int m = (wm << 6) + (fm << 4) + (kl << 2) + j;
        o[(size_t)m * 256 + n] = acc[fm][fn][j];
      }
    }
}

// ------------------------- softmax (wave per row) ---------------------------
// P[bh][i][j] = softmax_j(sum_{ks=0..7} Sp[8bh+ks] / 64), bf16 with 1/sum.

__global__ void softmax_k(const float* __restrict__ Sp, ushort* __restrict__ Pb) {
  const int w = threadIdx.x >> 6, l = threadIdx.x & 63;
  const int row = (blockIdx.x << 2) + w;        // 0..8191
  const int bh = row >> 8, i = row & 255;
  const float4* p0 = reinterpret_cast<const float4*>(
      Sp + (((size_t)bh << 3) << 16) + ((size_t)i << 8)) + l;
  float s0 = 0.f, s1 = 0.f, s2 = 0.f, s3 = 0.f;
#pragma unroll
  for (int ks = 0; ks < 8; ++ks) {
    float4 a = p0[(size_t)ks * 16384];
    s0 += a.x; s1 += a.y; s2 += a.z; s3 += a.w;
  }
  const float scale = 0.015625f;
  s0 *= scale; s1 *= scale; s2 *= scale; s3 *= scale;
  float m = fmaxf(fmaxf(s0, s1), fmaxf(s2, s3));
#pragma unroll
  for (int d2 = 1; d2 < 64; d2 <<= 1) m = fmaxf(m, __shfl_xor(m, d2));
  float e0 = __expf(s0 - m), e1 = __expf(s1 - m);
  float e2 = __expf(s2 - m), e3 = __expf(s3 - m);
  float sum = e0 + e1 + e2 + e3;
#pragma unroll
  for (int d2 = 1; d2 < 64; d2 <<= 1) sum += __shfl_xor(sum, d2);
  float r = 1.0f / sum;
  ushort4 p; p.x = f2bf(e0 * r); p.y = f2bf(e1 * r);
  p.z = f2bf(e2 * r); p.w = f2bf(e3 * r);
  reinterpret_cast<ushort4*>(Pb + ((size_t)bh << 16) + ((size_t)i << 8))[l] = p;
}

// ---------------------- gemm_pv: O = P V  (A=Vt, B=P) -----------------------
// 1024 blocks; XCD swizzle groups one bh's 32 blocks on one XCD.
// M=4096 (rd), N=256 (i), K=256. Writes O2[(b,r,i)][h*64+d] as ushort4.

__global__ __launch_bounds__(512, 4) void gemm_pv_k(
    const ushort* __restrict__ Vt, const ushort* __restrict__ Pb,
    ushort* __restrict__ O2) {
  __shared__ __align__(16) char lds[73728];
  f32x4 acc[4][4];
  const int Bid = blockIdx.x;
  const int xcd = Bid & 7, idx = Bid >> 3;      // idx 0..127
  const int sub = idx & 31, grp = idx >> 5;     // sub: mt*2+nt, grp 0..3
  const int bh = (grp << 3) + xcd, b = bh >> 3, h = bh & 7;
  const int m0 = (sub >> 1) << 8;               // rd tile (16 x 256)
  const int n0 = (sub & 1) << 7;                // i tile (2 x 128)
  gemm_nt_256x128(Vt + ((size_t)bh << 20), Pb + ((size_t)bh << 16),
                  256, 256, 8, m0, n0, lds, acc);

  const int tid = threadIdx.x, w = tid >> 6, l = tid & 63;
  const int il = l & 15, kl = l >> 4;
  const int wm = w >> 1, wn = w & 1;
#pragma unroll
  for (int fm = 0; fm < 4; ++fm) {
    int rd0 = m0 + (wm << 6) + (fm << 4) + (kl << 2);
    int r = rd0 >> 6, d0 = rd0 & 63;
#pragma unroll
    for (int fn = 0; fn < 4; ++fn) {
      int i = n0 + (wn << 6) + (fn << 4) + il;
      ushort4 pk; pk.x = f2bf(acc[fm][fn][0]); pk.y = f2bf(acc[fm][fn][1]);
      pk.z = f2bf(acc[fm][fn][2]); pk.w = f2bf(acc[fm][fn][3]);
      *reinterpret_cast<ushort4*>(
          O2 + ((size_t)((((b << 6) + r) << 8) + i) << 9) + (h << 6) + d0) = pk;
    }
  }
}

// ------------------------------- launcher -----------------------------------

extern "C" void kernel_launch(void* const* d_in, const int* in_sizes, int n_in,
                              void* d_out, int out_size, void* d_ws, size_t ws_size,
                              hipStream_t stream) {
  const float* x    = (const float*)d_in[0];
  const float* Wqkv = (const float*)d_in[1];
  const float* W0   = (const float*)d_in[2];
  float* out = (float*)d_out;

  char* ws = (char*)d_ws;
  ushort* xb  = (ushort*)(ws);                    // 67,108,864 B (-> Sp -> O2)
  ushort* Wp  = (ushort*)(ws + 67108864);         //  1,572,864
  ushort* W0b = (ushort*)(ws + 68681728);         //    524,288
  ushort* Qb  = (ushort*)(ws + 69206016);         // 67,108,864 (-> Pb)
  ushort* Kb  = (ushort*)(ws + 136314880);        // 67,108,864
  ushort* Vt  = (ushort*)(ws + 203423744);        // 67,108,864  -> total 270,532,608
  if (ws_size < 270532608ull) return;             // workspace too small: fail visibly

  cast_f32_to_bf16<<<2048, 256, 0, stream>>>(x, xb, 8388608);
  cast_f32_to_bf16<<<256, 256, 0, stream>>>(W0, W0b, 65536);
  permute_wqkv_k<<<1536, 128, 0, stream>>>(Wqkv, Wp);

  gemm_qkv_k<<<3072, 512, 0, stream>>>(xb, Wp, Qb, Kb, Vt);

  float*  Sp = (float*)xb;                        // xb dead after gemm1 (64 MB)
  ushort* Pb = Qb;                                // Qb dead after gemm_s (8.4 MB)
  ushort* O2 = xb;                                // Sp dead after softmax (64 MB)

  gemm_s_k<<<512, 512, 0, stream>>>(Qb, Kb, Sp);
  softmax_k<<<2048, 256, 0, stream>>>(Sp, Pb);
  gemm_pv_k<<<1024, 512, 0, stream>>>(Vt, Pb, O2);

  gemm_out_k<<<1024, 512, 0, stream>>>(O2, W0b, out);
}

// Round 7
// 303.122 us; speedup vs baseline: 1.2228x; 1.0056x over previous
//
#include <hip/hip_runtime.h>

// ---------------------------------------------------------------------------
// TiedRowAxialAttention on MI355X (gfx950), bf16 MFMA pipeline.
// dims: b=4 rows=64 t=256 dim=512 heads=8 dim_head=64 ; scale = 1/64
// stages:
//   prep:   x->bf16 ; W_qkv permuted (d,k,h)->(k,h,d) + bf16 ; W0->bf16
//   gemm1:  qkv = x @ Wp^T (M=65536,N=1536,K=512) -> Q[bh][i][rd], K[bh][j][rd],
//           Vt[bh][rd][j]
//   gemm_s: S[bh][i][j] = sum_rd Q K (batched NT, split-K=8, fp32 partials)
//   softmax: wave-per-row, P = softmax(S/64) bf16 (rinv folded in)
//   gemm_pv: O = P V via A=Vt,B=P (M=4096 rd, N=256 i, K=256) -> O2[(b,r,i)][hd]
//   gemm2:  out = O2 @ W0^T -> fp32
// Shared mainloop: 256x128 tile, BK=32, 4 waves (2Mx2N), per-wave 128x64
// (acc[8][4], reads/MFMA=0.375), 3 LDS buffers (72 KB) -> 2 blocks/CU,
// 2-tile prefetch lead, counted vmcnt(6), one barrier per K-tile.
// ---------------------------------------------------------------------------

typedef short  bf16x8 __attribute__((ext_vector_type(8)));
typedef float  f32x4  __attribute__((ext_vector_type(4)));

#define MFMA16(a,b,c) __builtin_amdgcn_mfma_f32_16x16x32_bf16((a),(b),(c),0,0,0)

__device__ __forceinline__ ushort f2bf(float f) {
  union { float f; unsigned u; } v; v.f = f;
  unsigned r = v.u + 0x7fffu + ((v.u >> 16) & 1u);   // RNE
  return (ushort)(r >> 16);
}

__device__ __forceinline__ void gload_lds16(const void* g, void* lds) {
  __builtin_amdgcn_global_load_lds(
      (const __attribute__((address_space(1))) void*)g,
      (__attribute__((address_space(3))) void*)lds, 16, 0, 0);
}

// -------------------------------- prep -------------------------------------

__global__ void cast_f32_to_bf16(const float* __restrict__ in,
                                 ushort* __restrict__ out, int n4) {
  int idx = blockIdx.x * blockDim.x + threadIdx.x;
  int stride = gridDim.x * blockDim.x;
  for (int v = idx; v < n4; v += stride) {
    float4 f = reinterpret_cast<const float4*>(in)[v];
    ushort4 o; o.x = f2bf(f.x); o.y = f2bf(f.y); o.z = f2bf(f.z); o.w = f2bf(f.w);
    reinterpret_cast<ushort4*>(out)[v] = o;
  }
}

// Wp[n'][c], n' = (k*8+h)*64+d  <-  W_qkv[d*24+k*8+h][c]
__global__ void permute_wqkv_k(const float* __restrict__ W, ushort* __restrict__ Wp) {
  int np = blockIdx.x;                    // 0..1535
  int k = np >> 9, h = (np >> 6) & 7, d = np & 63;
  const float4* s = reinterpret_cast<const float4*>(W + (size_t)(d * 24 + k * 8 + h) * 512);
  ushort4* o = reinterpret_cast<ushort4*>(Wp + (size_t)np * 512);
  for (int c = threadIdx.x; c < 128; c += blockDim.x) {
    float4 f = s[c];
    ushort4 u; u.x = f2bf(f.x); u.y = f2bf(f.y); u.z = f2bf(f.z); u.w = f2bf(f.w);
    o[c] = u;
  }
}

// ================== 256x128 pipelined NT mainloop (4 waves) =================
// C = A @ B^T ; A [M][lda], B [N][ldb] bf16 row-major, K = 32*P.
// 256 threads = 4 waves (2M x 2N), per-wave 128x64 out = acc[8][4] 16x16 frags.
// BK=32, 3 LDS buffers (A 16KB + B 8KB each = 24KB), 2-tile prefetch lead,
// counted vmcnt(6) once per K-tile, one barrier per K-tile.
// LDS per-row slot rotation: storage slot t at row r holds k-slot (t - r>>1)&3
// (stage source pre-rotated; reads use slot (kl + r>>1)&3) -> conflict-free.

__device__ __forceinline__ void gemm_nt_256x128(
    const ushort* __restrict__ A, const ushort* __restrict__ B,
    int lda, int ldb, int P, int m0, int n0, char* lds, f32x4 (&acc)[8][4]) {
  const int tid = threadIdx.x;
  const int w = tid >> 6, l = tid & 63;
  const int il = l & 15, kl = l >> 4;
  const int wm = w >> 1, wn = w & 1;

  auto stageA = [&](char* buf, int kt) {
#pragma unroll
    for (int c = 0; c < 4; ++c) {
      int rbase = (w << 6) + (c << 4);                     // wave-uniform
      int row = rbase + (l >> 2);
      int s = ((l & 3) - ((row >> 1) & 3)) & 3;
      gload_lds16(A + (size_t)(m0 + row) * lda + (kt << 5) + (s << 3),
                  buf + rbase * 64);
    }
  };
  auto stageB = [&](char* buf, int kt) {
#pragma unroll
    for (int c = 0; c < 2; ++c) {
      int rbase = (w << 5) + (c << 4);                     // wave-uniform
      int row = rbase + (l >> 2);
      int s = ((l & 3) - ((row >> 1) & 3)) & 3;
      gload_lds16(B + (size_t)(n0 + row) * ldb + (kt << 5) + (s << 3),
                  buf + 16384 + rbase * 64);
    }
  };
  auto loadA8 = [&](const char* buf, bf16x8 (&af)[8]) {
#pragma unroll
    for (int q = 0; q < 8; ++q) {
      int row = (wm << 7) + (q << 4) + il;
      af[q] = *(const bf16x8*)(buf + row * 64 + (((kl + (row >> 1)) & 3) << 4));
    }
  };
  auto loadB4 = [&](const char* buf, bf16x8 (&bfr)[4]) {
#pragma unroll
    for (int q = 0; q < 4; ++q) {
      int row = (wn << 6) + (q << 4) + il;
      bfr[q] = *(const bf16x8*)(buf + 16384 + row * 64 + (((kl + (row >> 1)) & 3) << 4));
    }
  };

#pragma unroll
  for (int i = 0; i < 8; ++i)
#pragma unroll
    for (int j = 0; j < 4; ++j) acc[i][j] = f32x4{0.f, 0.f, 0.f, 0.f};

  // prologue: stage tiles 0,1 (6 vmem ops each); t0 must be resident.
  stageA(lds, 0);         stageB(lds, 0);
  stageA(lds + 24576, 1); stageB(lds + 24576, 1);
  asm volatile("s_waitcnt vmcnt(6)" ::: "memory");
  __builtin_amdgcn_s_barrier();

  int cur = 0, nx = 2;
  for (int g = 0; g < P; ++g) {
    char* cbuf = lds + cur * 24576;
    char* sbuf = lds + nx * 24576;
    bf16x8 af[8], bfr[4];
    loadA8(cbuf, af);
    loadB4(cbuf, bfr);
    if (g + 2 < P) { stageA(sbuf, g + 2); stageB(sbuf, g + 2); }
    asm volatile("s_waitcnt lgkmcnt(0)" ::: "memory");
    __builtin_amdgcn_sched_barrier(0);
    __builtin_amdgcn_s_setprio(1);
#pragma unroll
    for (int fm = 0; fm < 8; ++fm)
#pragma unroll
      for (int fn = 0; fn < 4; ++fn)
        acc[fm][fn] = MFMA16(af[fm], bfr[fn], acc[fm][fn]);
    __builtin_amdgcn_s_setprio(0);
    if (g + 2 < P) asm volatile("s_waitcnt vmcnt(6)" ::: "memory");
    else           asm volatile("s_waitcnt vmcnt(0)" ::: "memory");
    __builtin_amdgcn_s_barrier();
    cur = (cur == 2) ? 0 : cur + 1;
    nx  = (nx  == 2) ? 0 : nx  + 1;
  }
}

// ------------------------------- gemm1 (qkv) --------------------------------
// 3072 blocks; XCD swizzle: the 12 n-tiles of one A-panel group stay together.

__global__ __launch_bounds__(256, 2) void gemm_qkv_k(
    const ushort* __restrict__ xb, const ushort* __restrict__ Wp,
    ushort* __restrict__ Qb, ushort* __restrict__ Kb, ushort* __restrict__ Vt) {
  __shared__ __align__(16) char lds[73728];
  f32x4 acc[8][4];
  const int Bid = blockIdx.x;
  const int xcd = Bid & 7, idx = Bid >> 3;
  const int nt = idx % 12, pl = idx / 12;       // pl 0..31
  const int m0 = ((pl << 3) + xcd) << 8;        // 256 m-tiles * 256
  const int n0 = nt << 7;
  gemm_nt_256x128(xb, Wp, 512, 512, 16, m0, n0, lds, acc);

  const int tid = threadIdx.x, w = tid >> 6, l = tid & 63;
  const int il = l & 15, kl = l >> 4;
  const int wm = w >> 1, wn = w & 1;
  const int kq = n0 >> 9;                       // block-uniform: 0=Q 1=K 2=V
  const int br = m0 >> 8, b = br >> 6, r = br & 63;   // one (b,r) per block

  if (kq < 2) {
    ushort* dstb = kq ? Kb : Qb;
#pragma unroll
    for (int fm = 0; fm < 8; ++fm)
#pragma unroll
      for (int fn = 0; fn < 4; ++fn) {
        int n = n0 + (wn << 6) + (fn << 4) + il;
        int h = (n >> 6) & 7, d = n & 63;
#pragma unroll
        for (int j = 0; j < 4; ++j) {
          int i = (wm << 7) + (fm << 4) + (kl << 2) + j;
          size_t dst = ((size_t)((((b << 3) + h) << 8) + i) << 12) + (r << 6) + d;
          dstb[dst] = f2bf(acc[fm][fn][j]);     // lanes: 2B x16 contiguous in d
        }
      }
  } else {
#pragma unroll
    for (int fm = 0; fm < 8; ++fm)
#pragma unroll
      for (int fn = 0; fn < 4; ++fn) {
        int n = n0 - 1024 + (wn << 6) + (fn << 4) + il;     // h*64+d
        int h = n >> 6, d = n & 63;
        int i0 = (wm << 7) + (fm << 4) + (kl << 2);
        size_t dst = (((size_t)((((b << 3) + h) << 12)) + (r << 6) + d) << 8) + i0;
        ushort4 pk; pk.x = f2bf(acc[fm][fn][0]); pk.y = f2bf(acc[fm][fn][1]);
        pk.z = f2bf(acc[fm][fn][2]); pk.w = f2bf(acc[fm][fn][3]);
        *reinterpret_cast<ushort4*>(&Vt[dst]) = pk;   // 4 consecutive i
      }
  }
}

// ------------------------------- gemm2 (out) --------------------------------
// 1024 blocks; XCD swizzle; scalar f32 stores (lanes 4B x16 contiguous).

__global__ __launch_bounds__(256, 2) void gemm_out_k(
    const ushort* __restrict__ O2, const ushort* __restrict__ W0b,
    float* __restrict__ out) {
  __shared__ __align__(16) char lds[73728];
  f32x4 acc[8][4];
  const int Bid = blockIdx.x;
  const int xcd = Bid & 7, idx = Bid >> 3;
  const int nt = idx & 3, pl = idx >> 2;        // pl 0..31
  const int m0 = ((pl << 3) + xcd) << 8;
  const int n0 = nt << 7;
  gemm_nt_256x128(O2, W0b, 512, 512, 16, m0, n0, lds, acc);

  const int tid = threadIdx.x, w = tid >> 6, l = tid & 63;
  const int il = l & 15, kl = l >> 4;
  const int wm = w >> 1, wn = w & 1;
#pragma unroll
  for (int fm = 0; fm < 8; ++fm)
#pragma unroll
    for (int fn = 0; fn < 4; ++fn) {
      int n = n0 + (wn << 6) + (fn << 4) + il;
#pragma unroll
      for (int j = 0; j < 4; ++j) {
        int m = m0 + (wm << 7) + (fm << 4) + (kl << 2) + j;
        out[(size_t)m * 512 + n] = acc[fm][fn][j];
      }
    }
}

// ---------------------- gemm_s: S partials (split-K=8) ----------------------
// 512 blocks; z = bh*8+ks, each computes a 256x128 slab of S over rd-range
// ks*512..+512. Sp[z][i][j] fp32.

__global__ __launch_bounds__(256, 2) void gemm_s_k(
    const ushort* __restrict__ Qb, const ushort* __restrict__ Kb,
    float* __restrict__ Sp) {
  __shared__ __align__(16) char lds[73728];
  f32x4 acc[8][4];
  const int Bid = blockIdx.x;
  const int xcd = Bid & 7, idx = Bid >> 3;      // idx 0..63
  const int nt = idx & 1, zl = idx >> 1;        // zl 0..31
  const int z = (zl << 3) + xcd;                // 0..255
  const int bh = z >> 3, ks = z & 7;
  const int n0 = nt << 7;
  const size_t base = ((size_t)bh << 20) + ((size_t)ks << 9);
  gemm_nt_256x128(Qb + base, Kb + base, 4096, 4096, 16, 0, n0, lds, acc);

  const int tid = threadIdx.x, w = tid >> 6, l = tid & 63;
  const int il = l & 15, kl = l >> 4;
  const int wm = w >> 1, wn = w & 1;
  float* o = Sp + ((size_t)z << 16);
#pragma unroll
  for (int fm = 0; fm < 8; ++fm)
#pragma unroll
    for (int fn = 0; fn < 4; ++fn) {
      int n = n0 + (wn << 6) + (fn << 4) + il;
#pragma unroll
      for (int j = 0; j < 4; ++j) {
        int m = (wm << 7) + (fm << 4) + (kl << 2) + j;
        o[(size_t)m * 256 + n] = acc[fm][fn][j];
      }
    }
}

// ------------------------- softmax (wave per row) ---------------------------
// P[bh][i][j] = softmax_j(sum_{ks=0..7} Sp[8bh+ks] / 64), bf16 with 1/sum.

__global__ void softmax_k(const float* __restrict__ Sp, ushort* __restrict__ Pb) {
  const int w = threadIdx.x >> 6, l = threadIdx.x & 63;
  const int row = (blockIdx.x << 2) + w;        // 0..8191
  const int bh = row >> 8, i = row & 255;
  const float4* p0 = reinterpret_cast<const float4*>(
      Sp + (((size_t)bh << 3) << 16) + ((size_t)i << 8)) + l;
  float s0 = 0.f, s1 = 0.f, s2 = 0.f, s3 = 0.f;
#pragma unroll
  for (int ks = 0; ks < 8; ++ks) {
    float4 a = p0[(size_t)ks * 16384];
    s0 += a.x; s1 += a.y; s2 += a.z; s3 += a.w;
  }
  const float scale = 0.015625f;
  s0 *= scale; s1 *= scale; s2 *= scale; s3 *= scale;
  float m = fmaxf(fmaxf(s0, s1), fmaxf(s2, s3));
#pragma unroll
  for (int d2 = 1; d2 < 64; d2 <<= 1) m = fmaxf(m, __shfl_xor(m, d2));
  float e0 = __expf(s0 - m), e1 = __expf(s1 - m);
  float e2 = __expf(s2 - m), e3 = __expf(s3 - m);
  float sum = e0 + e1 + e2 + e3;
#pragma unroll
  for (int d2 = 1; d2 < 64; d2 <<= 1) sum += __shfl_xor(sum, d2);
  float r = 1.0f / sum;
  ushort4 p; p.x = f2bf(e0 * r); p.y = f2bf(e1 * r);
  p.z = f2bf(e2 * r); p.w = f2bf(e3 * r);
  reinterpret_cast<ushort4*>(Pb + ((size_t)bh << 16) + ((size_t)i << 8))[l] = p;
}

// ---------------------- gemm_pv: O = P V  (A=Vt, B=P) -----------------------
// 1024 blocks; XCD swizzle groups one bh's 32 blocks on one XCD.
// M=4096 (rd), N=256 (i), K=256. Writes O2[(b,r,i)][h*64+d] as ushort4.

__global__ __launch_bounds__(256, 2) void gemm_pv_k(
    const ushort* __restrict__ Vt, const ushort* __restrict__ Pb,
    ushort* __restrict__ O2) {
  __shared__ __align__(16) char lds[73728];
  f32x4 acc[8][4];
  const int Bid = blockIdx.x;
  const int xcd = Bid & 7, idx = Bid >> 3;      // idx 0..127
  const int sub = idx & 31, grp = idx >> 5;     // sub: mt*2+nt, grp 0..3
  const int bh = (grp << 3) + xcd, b = bh >> 3, h = bh & 7;
  const int m0 = (sub >> 1) << 8;               // rd tile (16 x 256)
  const int n0 = (sub & 1) << 7;                // i tile (2 x 128)
  gemm_nt_256x128(Vt + ((size_t)bh << 20), Pb + ((size_t)bh << 16),
                  256, 256, 8, m0, n0, lds, acc);

  const int tid = threadIdx.x, w = tid >> 6, l = tid & 63;
  const int il = l & 15, kl = l >> 4;
  const int wm = w >> 1, wn = w & 1;
#pragma unroll
  for (int fm = 0; fm < 8; ++fm) {
    int rd0 = m0 + (wm << 7) + (fm << 4) + (kl << 2);
    int r = rd0 >> 6, d0 = rd0 & 63;
#pragma unroll
    for (int fn = 0; fn < 4; ++fn) {
      int i = n0 + (wn << 6) + (fn << 4) + il;
      ushort4 pk; pk.x = f2bf(acc[fm][fn][0]); pk.y = f2bf(acc[fm][fn][1]);
      pk.z = f2bf(acc[fm][fn][2]); pk.w = f2bf(acc[fm][fn][3]);
      *reinterpret_cast<ushort4*>(
          O2 + ((size_t)((((b << 6) + r) << 8) + i) << 9) + (h << 6) + d0) = pk;
    }
  }
}

// ------------------------------- launcher -----------------------------------

extern "C" void kernel_launch(void* const* d_in, const int* in_sizes, int n_in,
                              void* d_out, int out_size, void* d_ws, size_t ws_size,
                              hipStream_t stream) {
  const float* x    = (const float*)d_in[0];
  const float* Wqkv = (const float*)d_in[1];
  const float* W0   = (const float*)d_in[2];
  float* out = (float*)d_out;

  char* ws = (char*)d_ws;
  ushort* xb  = (ushort*)(ws);                    // 67,108,864 B (-> Sp -> O2)
  ushort* Wp  = (ushort*)(ws + 67108864);         //  1,572,864
  ushort* W0b = (ushort*)(ws + 68681728);         //    524,288
  ushort* Qb  = (ushort*)(ws + 69206016);         // 67,108,864 (-> Pb)
  ushort* Kb  = (ushort*)(ws + 136314880);        // 67,108,864
  ushort* Vt  = (ushort*)(ws + 203423744);        // 67,108,864  -> total 270,532,608
  if (ws_size < 270532608ull) return;             // workspace too small: fail visibly

  cast_f32_to_bf16<<<2048, 256, 0, stream>>>(x, xb, 8388608);
  cast_f32_to_bf16<<<256, 256, 0, stream>>>(W0, W0b, 65536);
  permute_wqkv_k<<<1536, 128, 0, stream>>>(Wqkv, Wp);

  gemm_qkv_k<<<3072, 256, 0, stream>>>(xb, Wp, Qb, Kb, Vt);

  float*  Sp = (float*)xb;                        // xb dead after gemm1 (64 MB)
  ushort* Pb = Qb;                                // Qb dead after gemm_s (8.4 MB)
  ushort* O2 = xb;                                // Sp dead after softmax (64 MB)

  gemm_s_k<<<512, 256, 0, stream>>>(Qb, Kb, Sp);
  softmax_k<<<2048, 256, 0, stream>>>(Sp, Pb);
  gemm_pv_k<<<1024, 256, 0, stream>>>(Vt, Pb, O2);

  gemm_out_k<<<1024, 256, 0, stream>>>(O2, W0b, out);
}